// Round 1
// baseline (743.135 us; speedup 1.0000x reference)
//
#include <hip/hip_runtime.h>
#include <cmath>

// Problem constants
#define NBATCH 16
#define NCH    128      // C = channels = HIDDEN
#define NPIX   16384    // H*W
// Workspace layout (float offsets)
//   S : [16][128]          exp-row-sums          off 0      (2048 floats)
//   A : [16][4][32][32]    sum exp(k)*v partials off 2048   (65536 floats)
//   M : [16][128][128]     fused matrix M'       off 67584  (262144 floats)
#define WS_S_OFF 0
#define WS_A_OFF 2048
#define WS_M_OFF 67584
#define WS_ZERO_BYTES ((2048 + 65536) * 4)

// ---------------------------------------------------------------------------
// K1: per (batch, 64-wide n-chunk): kv = Wkv @ X  (256x64, K=128 SGEMM),
//     E = exp(k-part), partial S (row sums of E) and A_h = E_h V_h^T, atomics.
// ---------------------------------------------------------------------------
__global__ __launch_bounds__(256, 2) void k1_partials(const float* __restrict__ x,
                                                      const float* __restrict__ w_qkv,
                                                      float* __restrict__ ws)
{
    const int b  = blockIdx.y;
    const int n0 = blockIdx.x * 64;
    const int t  = threadIdx.x;

    __shared__ union {
        struct { float Ws[16][256]; float Xs[16][64]; } st;  // GEMM staging (20.5 KB)
        float EV[256][68];                                   // E rows 0..127, V rows 128..255 (69.6 KB)
    } sm;

    const int rg  = t >> 3;       // 0..31 -> rows rg*8..rg*8+7 (of 256)
    const int cg  = t & 7;        // 0..7  -> cols cg*8..cg*8+7 (of 64)
    const int r0  = rg * 8;
    const int nn0 = cg * 8;

    float acc[8][8];
#pragma unroll
    for (int j = 0; j < 8; ++j)
#pragma unroll
        for (int i = 0; i < 8; ++i) acc[j][i] = 0.f;

    const float* wkv = w_qkv + 128 * NCH;  // rows 128..383 = Wk then Wv

    for (int kt = 0; kt < 8; ++kt) {
        const int k0 = kt * 16;
        // stage Ws[kk][r] = wkv[r][k0+kk] : thread t loads row t, 16 contiguous c
        {
            const float* src = wkv + t * NCH + k0;
            float4 a0 = *(const float4*)(src + 0);
            float4 a1 = *(const float4*)(src + 4);
            float4 a2 = *(const float4*)(src + 8);
            float4 a3 = *(const float4*)(src + 12);
            sm.st.Ws[ 0][t] = a0.x; sm.st.Ws[ 1][t] = a0.y; sm.st.Ws[ 2][t] = a0.z; sm.st.Ws[ 3][t] = a0.w;
            sm.st.Ws[ 4][t] = a1.x; sm.st.Ws[ 5][t] = a1.y; sm.st.Ws[ 6][t] = a1.z; sm.st.Ws[ 7][t] = a1.w;
            sm.st.Ws[ 8][t] = a2.x; sm.st.Ws[ 9][t] = a2.y; sm.st.Ws[10][t] = a2.z; sm.st.Ws[11][t] = a2.w;
            sm.st.Ws[12][t] = a3.x; sm.st.Ws[13][t] = a3.y; sm.st.Ws[14][t] = a3.z; sm.st.Ws[15][t] = a3.w;
        }
        // stage Xs[kk][n] = x[b][k0+kk][n0+n]
        {
            const int kk = t >> 4;
            const int nq = (t & 15) * 4;
            *(float4*)&sm.st.Xs[kk][nq] =
                *(const float4*)(x + (size_t)(b * NCH + k0 + kk) * NPIX + n0 + nq);
        }
        __syncthreads();
#pragma unroll
        for (int kk = 0; kk < 16; ++kk) {
            float wv[8], xv[8];
            *(float4*)&wv[0] = *(const float4*)&sm.st.Ws[kk][r0];
            *(float4*)&wv[4] = *(const float4*)&sm.st.Ws[kk][r0 + 4];
            *(float4*)&xv[0] = *(const float4*)&sm.st.Xs[kk][nn0];
            *(float4*)&xv[4] = *(const float4*)&sm.st.Xs[kk][nn0 + 4];
#pragma unroll
            for (int j = 0; j < 8; ++j)
#pragma unroll
                for (int i = 0; i < 8; ++i) acc[j][i] = fmaf(wv[j], xv[i], acc[j][i]);
        }
        __syncthreads();
    }

    // exp on k-rows (rows 0..127); wave-uniform branch (t<128 == waves 0,1)
    if (r0 < 128) {
#pragma unroll
        for (int j = 0; j < 8; ++j)
#pragma unroll
            for (int i = 0; i < 8; ++i) acc[j][i] = expf(acc[j][i]);
    }
    // spill tile to LDS (aliases staging; safe: last reads fenced by syncthreads above)
#pragma unroll
    for (int j = 0; j < 8; ++j) {
        *(float4*)&sm.EV[r0 + j][nn0]     = make_float4(acc[j][0], acc[j][1], acc[j][2], acc[j][3]);
        *(float4*)&sm.EV[r0 + j][nn0 + 4] = make_float4(acc[j][4], acc[j][5], acc[j][6], acc[j][7]);
    }
    __syncthreads();

    // S partials: row sums of E
    if (t < 128) {
        float s = 0.f;
#pragma unroll
        for (int n = 0; n < 64; n += 4) {
            float4 e4 = *(const float4*)&sm.EV[t][n];
            s += (e4.x + e4.y) + (e4.z + e4.w);
        }
        atomicAdd(&ws[WS_S_OFF + b * 128 + t], s);
    }

    // A partials: per head h, A[d][e] += sum_n E[h*32+d][n] * V[h*32+e][n]
    {
        const int h   = t >> 6;          // wave w -> head w
        const int sub = t & 63;
        const int d0  = (sub >> 3) * 4;  // 0,4,..,28
        const int e0  = (sub & 7) * 4;   // 0,4,..,28
        float a4[4][4];
#pragma unroll
        for (int j = 0; j < 4; ++j)
#pragma unroll
            for (int i = 0; i < 4; ++i) a4[j][i] = 0.f;

        for (int n = 0; n < 64; n += 4) {
            float4 er[4], vr[4];
#pragma unroll
            for (int j = 0; j < 4; ++j) er[j] = *(const float4*)&sm.EV[h * 32 + d0 + j][n];
#pragma unroll
            for (int j = 0; j < 4; ++j) vr[j] = *(const float4*)&sm.EV[128 + h * 32 + e0 + j][n];
#pragma unroll
            for (int dj = 0; dj < 4; ++dj)
#pragma unroll
                for (int ej = 0; ej < 4; ++ej) {
                    a4[dj][ej] = fmaf(er[dj].x, vr[ej].x, a4[dj][ej]);
                    a4[dj][ej] = fmaf(er[dj].y, vr[ej].y, a4[dj][ej]);
                    a4[dj][ej] = fmaf(er[dj].z, vr[ej].z, a4[dj][ej]);
                    a4[dj][ej] = fmaf(er[dj].w, vr[ej].w, a4[dj][ej]);
                }
        }
        float* Ab = ws + WS_A_OFF + (size_t)((b * 4 + h) * 32) * 32;
#pragma unroll
        for (int dj = 0; dj < 4; ++dj)
#pragma unroll
            for (int ej = 0; ej < 4; ++ej)
                atomicAdd(&Ab[(d0 + dj) * 32 + (e0 + ej)], a4[dj][ej]);
    }
}

// ---------------------------------------------------------------------------
// K2: per (batch, 32-row o-slab): context = A/S; T[o][hd] = sum_e w_out*ctx;
//     M'[o][c] = scale * sum_hd T[o][hd] * Wq[hd][c]
// ---------------------------------------------------------------------------
__global__ __launch_bounds__(256) void k2_mprime(const float* __restrict__ w_qkv,
                                                 const float* __restrict__ w_out,
                                                 float* __restrict__ ws)
{
    const int b  = blockIdx.x;
    const int o0 = blockIdx.y * 32;
    const int t  = threadIdx.x;

    __shared__ float ctx[4][32][32];  // [h][d][e]
    __shared__ float Ts[32][128];     // [oo][hd]
    __shared__ float Ss[128];

    if (t < 128) Ss[t] = ws[WS_S_OFF + b * 128 + t];
    __syncthreads();

    for (int i = t; i < 4096; i += 256) {
        const int h = i >> 10, d = (i >> 5) & 31, e = i & 31;
        ctx[h][d][e] = ws[WS_A_OFF + (size_t)b * 4096 + i] / Ss[h * 32 + d];
    }
    __syncthreads();

    // T rows for this o-slab: thread -> (oo = t>>3, 16 consecutive hd)
    {
        const int oo  = t >> 3;
        const int o   = o0 + oo;
        const int hd0 = (t & 7) * 16;
        const int h   = hd0 >> 5;       // fixed per thread
        const int db  = hd0 & 31;
        float wo[32];
#pragma unroll
        for (int e4 = 0; e4 < 32; e4 += 4)
            *(float4*)&wo[e4] = *(const float4*)&w_out[o * NCH + h * 32 + e4];
#pragma unroll
        for (int k = 0; k < 16; ++k) {
            const int d = db + k;
            float s = 0.f;
#pragma unroll
            for (int e = 0; e < 32; ++e) s = fmaf(wo[e], ctx[h][d][e], s);
            Ts[oo][hd0 + k] = s;
        }
    }
    __syncthreads();

    const float scale = 0.17677669529663687f;  // 32^-0.5
    for (int i = t; i < 32 * 128; i += 256) {
        const int oo = i >> 7;
        const int c  = i & 127;
        float s = 0.f;
#pragma unroll 8
        for (int hd = 0; hd < 128; ++hd) s = fmaf(Ts[oo][hd], w_qkv[hd * NCH + c], s);
        ws[WS_M_OFF + (size_t)(b * 128 + o0 + oo) * 128 + c] = s * scale;
    }
}

// ---------------------------------------------------------------------------
// K3: y[b] = M'[b] @ X[b] + bias   (128 x 16384, K=128 SGEMM per batch)
// ---------------------------------------------------------------------------
__global__ __launch_bounds__(256, 2) void k3_out(const float* __restrict__ x,
                                                 const float* __restrict__ bias,
                                                 const float* __restrict__ ws,
                                                 float* __restrict__ y)
{
    const int b  = blockIdx.y;
    const int n0 = blockIdx.x * 128;
    const int t  = threadIdx.x;

    __shared__ float Ms[16][128];
    __shared__ float Xs[16][132];   // padded (row shift 4 banks) to soften 4-way conflicts

    const float* Mp = ws + WS_M_OFF + (size_t)b * 128 * 128;

    const int rg  = t >> 4;        // 0..15 -> rows rg*8..+7
    const int cg  = t & 15;        // 0..15 -> cols cg*8..+7
    const int r0  = rg * 8;
    const int nn0 = cg * 8;

    float acc[8][8];
#pragma unroll
    for (int j = 0; j < 8; ++j)
#pragma unroll
        for (int i = 0; i < 8; ++i) acc[j][i] = 0.f;

    for (int kt = 0; kt < 8; ++kt) {
        const int k0 = kt * 16;
        // stage Ms[kk][r]: thread t -> row t&127, 8 floats at kk0=(t>>7)*8
        {
            const int r   = t & 127;
            const int kk0 = (t >> 7) * 8;
            const float* src = Mp + r * 128 + k0 + kk0;
            float4 a0 = *(const float4*)src;
            float4 a1 = *(const float4*)(src + 4);
            Ms[kk0 + 0][r] = a0.x; Ms[kk0 + 1][r] = a0.y; Ms[kk0 + 2][r] = a0.z; Ms[kk0 + 3][r] = a0.w;
            Ms[kk0 + 4][r] = a1.x; Ms[kk0 + 5][r] = a1.y; Ms[kk0 + 6][r] = a1.z; Ms[kk0 + 7][r] = a1.w;
        }
        // stage Xs[kk][n]: thread t -> kk=t>>4, 8 floats at nq=(t&15)*8
        {
            const int kk = t >> 4;
            const int nq = (t & 15) * 8;
            const float* src = x + (size_t)(b * NCH + k0 + kk) * NPIX + n0 + nq;
            *(float4*)&Xs[kk][nq]     = *(const float4*)src;
            *(float4*)&Xs[kk][nq + 4] = *(const float4*)(src + 4);
        }
        __syncthreads();
#pragma unroll
        for (int kk = 0; kk < 16; ++kk) {
            float m[8], xv[8];
            *(float4*)&m[0]  = *(const float4*)&Ms[kk][r0];
            *(float4*)&m[4]  = *(const float4*)&Ms[kk][r0 + 4];
            *(float4*)&xv[0] = *(const float4*)&Xs[kk][nn0];
            *(float4*)&xv[4] = *(const float4*)&Xs[kk][nn0 + 4];
#pragma unroll
            for (int j = 0; j < 8; ++j)
#pragma unroll
                for (int i = 0; i < 8; ++i) acc[j][i] = fmaf(m[j], xv[i], acc[j][i]);
        }
        __syncthreads();
    }

#pragma unroll
    for (int j = 0; j < 8; ++j) {
        const float bj = bias[r0 + j];
        float* dst = y + (size_t)(b * 128 + r0 + j) * NPIX + n0 + nn0;
        *(float4*)dst       = make_float4(acc[j][0] + bj, acc[j][1] + bj, acc[j][2] + bj, acc[j][3] + bj);
        *(float4*)(dst + 4) = make_float4(acc[j][4] + bj, acc[j][5] + bj, acc[j][6] + bj, acc[j][7] + bj);
    }
}

extern "C" void kernel_launch(void* const* d_in, const int* in_sizes, int n_in,
                              void* d_out, int out_size, void* d_ws, size_t ws_size,
                              hipStream_t stream) {
    (void)in_sizes; (void)n_in; (void)out_size; (void)ws_size;
    const float* x     = (const float*)d_in[0];
    const float* w_qkv = (const float*)d_in[1];
    const float* w_out = (const float*)d_in[2];
    const float* b_out = (const float*)d_in[3];
    float* y  = (float*)d_out;
    float* ws = (float*)d_ws;

    // ws is poisoned 0xAA before every launch: zero the atomic accumulators
    hipMemsetAsync(d_ws, 0, WS_ZERO_BYTES, stream);

    k1_partials<<<dim3(NPIX / 64, NBATCH), 256, 0, stream>>>(x, w_qkv, ws);
    k2_mprime  <<<dim3(NBATCH, 4),         256, 0, stream>>>(w_qkv, w_out, ws);
    k3_out     <<<dim3(NPIX / 128, NBATCH), 256, 0, stream>>>(x, b_out, ws, y);
}

// Round 2
// 735.463 us; speedup vs baseline: 1.0104x; 1.0104x over previous
//
#include <hip/hip_runtime.h>
#include <cmath>

// Problem constants
#define NBATCH 16
#define NCH    128      // C = channels = HIDDEN
#define NPIX   16384    // H*W
#define NREP   4        // atomic replica slots (cuts same-address RMW chain depth)

// Workspace layout (float offsets)
//   Spart : [16][NREP][128]         exp-row-sum partials
//   Apart : [16][NREP][4][32][32]   sum exp(k)*v partials
//   M     : [16][128][128]          fused matrix M'
#define WS_S_OFF 0
#define WS_A_OFF (16 * NREP * 128)
#define WS_M_OFF (WS_A_OFF + 16 * NREP * 4096)
#define WS_ZERO_BYTES ((size_t)WS_M_OFF * 4)

// ---------------------------------------------------------------------------
// K1: 512 blocks = (32 n-groups) x (16 batches). Each block loops over 8
// chunks of 64 cols: kv = Wkv @ X (256x64, K=128 SGEMM), E = exp(k-part),
// S accumulated in registers (shuffle-reduced), A accumulated in registers
// across chunks; atomics only in the epilogue, to replica slot g&3.
// ---------------------------------------------------------------------------
__global__ __launch_bounds__(256, 2) void k1_partials(const float* __restrict__ x,
                                                      const float* __restrict__ w_qkv,
                                                      float* __restrict__ ws)
{
    const int b = blockIdx.y;
    const int g = blockIdx.x;      // 0..31
    const int t = threadIdx.x;

    __shared__ union {
        struct { float Ws[16][256]; float Xs[16][64]; } st;  // GEMM staging (20.5 KB)
        float EV[256][68];                                   // E rows 0..127, V rows 128..255
    } sm;

    const int rg  = t >> 3;       // 0..31 -> rows rg*8..+7 (of 256)
    const int cg  = t & 7;        // 0..7  -> cols cg*8..+7 (of 64)
    const int r0  = rg * 8;
    const int nn0 = cg * 8;

    // A-phase mapping: one wave per head
    const int h   = t >> 6;
    const int sub = t & 63;
    const int d0  = (sub >> 3) * 4;
    const int e0  = (sub & 7) * 4;

    float a4[4][4];               // persistent A accumulator
#pragma unroll
    for (int j = 0; j < 4; ++j)
#pragma unroll
        for (int i = 0; i < 4; ++i) a4[j][i] = 0.f;
    float s8[8];                  // persistent S accumulator (valid for rg<16)
#pragma unroll
    for (int j = 0; j < 8; ++j) s8[j] = 0.f;

    const float* wkv = w_qkv + 128 * NCH;  // rows 128..383 = Wk then Wv

    for (int ci = 0; ci < 8; ++ci) {
        const int n0 = (g + ci * 32) * 64;

        float acc[8][8];
#pragma unroll
        for (int j = 0; j < 8; ++j)
#pragma unroll
            for (int i = 0; i < 8; ++i) acc[j][i] = 0.f;

        for (int kt = 0; kt < 8; ++kt) {
            const int k0 = kt * 16;
            // stage Ws[kk][r] = wkv[r][k0+kk]
            {
                const float* src = wkv + t * NCH + k0;
                float4 a0 = *(const float4*)(src + 0);
                float4 a1 = *(const float4*)(src + 4);
                float4 a2 = *(const float4*)(src + 8);
                float4 a3 = *(const float4*)(src + 12);
                sm.st.Ws[ 0][t] = a0.x; sm.st.Ws[ 1][t] = a0.y; sm.st.Ws[ 2][t] = a0.z; sm.st.Ws[ 3][t] = a0.w;
                sm.st.Ws[ 4][t] = a1.x; sm.st.Ws[ 5][t] = a1.y; sm.st.Ws[ 6][t] = a1.z; sm.st.Ws[ 7][t] = a1.w;
                sm.st.Ws[ 8][t] = a2.x; sm.st.Ws[ 9][t] = a2.y; sm.st.Ws[10][t] = a2.z; sm.st.Ws[11][t] = a2.w;
                sm.st.Ws[12][t] = a3.x; sm.st.Ws[13][t] = a3.y; sm.st.Ws[14][t] = a3.z; sm.st.Ws[15][t] = a3.w;
            }
            // stage Xs[kk][n] = x[b][k0+kk][n0+n]
            {
                const int kk = t >> 4;
                const int nq = (t & 15) * 4;
                *(float4*)&sm.st.Xs[kk][nq] =
                    *(const float4*)(x + (size_t)(b * NCH + k0 + kk) * NPIX + n0 + nq);
            }
            __syncthreads();
#pragma unroll
            for (int kk = 0; kk < 16; ++kk) {
                float wv[8], xv[8];
                *(float4*)&wv[0] = *(const float4*)&sm.st.Ws[kk][r0];
                *(float4*)&wv[4] = *(const float4*)&sm.st.Ws[kk][r0 + 4];
                *(float4*)&xv[0] = *(const float4*)&sm.st.Xs[kk][nn0];
                *(float4*)&xv[4] = *(const float4*)&sm.st.Xs[kk][nn0 + 4];
#pragma unroll
                for (int j = 0; j < 8; ++j)
#pragma unroll
                    for (int i = 0; i < 8; ++i) acc[j][i] = fmaf(wv[j], xv[i], acc[j][i]);
            }
            __syncthreads();
        }

        // exp on k-rows + register S accumulation (waves 0,1 — wave-uniform)
        if (r0 < 128) {
#pragma unroll
            for (int j = 0; j < 8; ++j) {
                float rs = 0.f;
#pragma unroll
                for (int i = 0; i < 8; ++i) {
                    acc[j][i] = __expf(acc[j][i]);
                    rs += acc[j][i];
                }
                s8[j] += rs;
            }
        }
        // spill tile to LDS (aliases staging; fenced by loop-end syncthreads)
#pragma unroll
        for (int j = 0; j < 8; ++j) {
            *(float4*)&sm.EV[r0 + j][nn0]     = make_float4(acc[j][0], acc[j][1], acc[j][2], acc[j][3]);
            *(float4*)&sm.EV[r0 + j][nn0 + 4] = make_float4(acc[j][4], acc[j][5], acc[j][6], acc[j][7]);
        }
        __syncthreads();

        // A-phase: per head h, a4[dj][ej] += sum_n E[h*32+d0+dj][n] * V[h*32+e0+ej][n]
        for (int n = 0; n < 64; n += 4) {
            float4 er[4], vr[4];
#pragma unroll
            for (int j = 0; j < 4; ++j) er[j] = *(const float4*)&sm.EV[h * 32 + d0 + j][n];
#pragma unroll
            for (int j = 0; j < 4; ++j) vr[j] = *(const float4*)&sm.EV[128 + h * 32 + e0 + j][n];
#pragma unroll
            for (int dj = 0; dj < 4; ++dj)
#pragma unroll
                for (int ej = 0; ej < 4; ++ej) {
                    a4[dj][ej] = fmaf(er[dj].x, vr[ej].x, a4[dj][ej]);
                    a4[dj][ej] = fmaf(er[dj].y, vr[ej].y, a4[dj][ej]);
                    a4[dj][ej] = fmaf(er[dj].z, vr[ej].z, a4[dj][ej]);
                    a4[dj][ej] = fmaf(er[dj].w, vr[ej].w, a4[dj][ej]);
                }
        }
        __syncthreads();  // fence EV reads before next chunk's staging writes
    }

    // ---- epilogue: atomics to replica slot (chain depth = 8 per address) ----
    const int rep = g & (NREP - 1);

    if (r0 < 128) {
#pragma unroll
        for (int j = 0; j < 8; ++j) {
            float s = s8[j];
            s += __shfl_xor(s, 1);
            s += __shfl_xor(s, 2);
            s += __shfl_xor(s, 4);
            s8[j] = s;
        }
        if (cg == 0) {
            float* Sp = ws + WS_S_OFF + (size_t)(b * NREP + rep) * 128;
#pragma unroll
            for (int j = 0; j < 8; ++j) atomicAdd(&Sp[r0 + j], s8[j]);
        }
    }
    {
        float* Ab = ws + WS_A_OFF + (size_t)((b * NREP + rep) * 4 + h) * 1024;
#pragma unroll
        for (int dj = 0; dj < 4; ++dj)
#pragma unroll
            for (int ej = 0; ej < 4; ++ej)
                atomicAdd(&Ab[(d0 + dj) * 32 + (e0 + ej)], a4[dj][ej]);
    }
}

// ---------------------------------------------------------------------------
// K2: per (batch, 32-row o-slab): reduce replicas; context = A/S;
//     T[o][hd] = sum_e w_out*ctx;  M'[o][c] = scale * sum_hd T[o][hd]*Wq[hd][c]
//     Wq staged through LDS in 32-row slabs (avoids latency-bound global loop).
// ---------------------------------------------------------------------------
__global__ __launch_bounds__(256) void k2_mprime(const float* __restrict__ w_qkv,
                                                 const float* __restrict__ w_out,
                                                 float* __restrict__ ws)
{
    const int b  = blockIdx.x;
    const int o0 = blockIdx.y * 32;
    const int t  = threadIdx.x;

    __shared__ float ctx[4][32][32];  // [h][d][e]
    __shared__ float Ts[32][128];     // [oo][hd]
    __shared__ float Wqs[32][128];    // Wq slab
    __shared__ float Ss[128];

    if (t < 128) {
        float s = 0.f;
#pragma unroll
        for (int r = 0; r < NREP; ++r)
            s += ws[WS_S_OFF + (size_t)(b * NREP + r) * 128 + t];
        Ss[t] = s;
    }
    __syncthreads();

    for (int i = t; i < 4096; i += 256) {
        float a = 0.f;
#pragma unroll
        for (int r = 0; r < NREP; ++r)
            a += ws[WS_A_OFF + (size_t)(b * NREP + r) * 4096 + i];
        const int hh = i >> 10, d = (i >> 5) & 31, e = i & 31;
        ctx[hh][d][e] = a / Ss[hh * 32 + d];
    }
    __syncthreads();

    // T rows for this o-slab: thread -> (oo = t>>3, 16 consecutive hd)
    {
        const int oo  = t >> 3;
        const int o   = o0 + oo;
        const int hd0 = (t & 7) * 16;
        const int hh  = hd0 >> 5;
        const int db  = hd0 & 31;
        float wo[32];
#pragma unroll
        for (int e4 = 0; e4 < 32; e4 += 4)
            *(float4*)&wo[e4] = *(const float4*)&w_out[o * NCH + hh * 32 + e4];
#pragma unroll
        for (int k = 0; k < 16; ++k) {
            const int d = db + k;
            float s = 0.f;
#pragma unroll
            for (int e = 0; e < 32; ++e) s = fmaf(wo[e], ctx[hh][d][e], s);
            Ts[oo][hd0 + k] = s;
        }
    }
    __syncthreads();

    // M' = scale * Ts @ Wq, with Wq staged in 32-row LDS slabs
    float macc[16];
#pragma unroll
    for (int ii = 0; ii < 16; ++ii) macc[ii] = 0.f;

    for (int slab = 0; slab < 4; ++slab) {
        for (int i = t; i < 32 * 128; i += 256)
            Wqs[i >> 7][i & 127] = w_qkv[(size_t)(slab * 32 + (i >> 7)) * NCH + (i & 127)];
        __syncthreads();
#pragma unroll
        for (int ii = 0; ii < 16; ++ii) {
            const int i  = t + ii * 256;
            const int oo = i >> 7;
            const int c  = i & 127;
            float s = macc[ii];
#pragma unroll
            for (int k = 0; k < 32; ++k)
                s = fmaf(Ts[oo][slab * 32 + k], Wqs[k][c], s);
            macc[ii] = s;
        }
        __syncthreads();
    }

    const float scale = 0.17677669529663687f;  // 32^-0.5
#pragma unroll
    for (int ii = 0; ii < 16; ++ii) {
        const int i  = t + ii * 256;
        const int oo = i >> 7;
        const int c  = i & 127;
        ws[WS_M_OFF + (size_t)(b * 128 + o0 + oo) * 128 + c] = macc[ii] * scale;
    }
}

// ---------------------------------------------------------------------------
// K3: y[b] = M'[b] @ X[b] + bias  (128 x 16384, K=128 SGEMM per batch)
//     Split-column microtile (cols cg*4 and 64+cg*4) -> conflict-free Xs reads.
// ---------------------------------------------------------------------------
__global__ __launch_bounds__(256, 4) void k3_out(const float* __restrict__ x,
                                                 const float* __restrict__ bias,
                                                 const float* __restrict__ ws,
                                                 float* __restrict__ y)
{
    const int b  = blockIdx.y;
    const int n0 = blockIdx.x * 128;
    const int t  = threadIdx.x;

    __shared__ float Ms[16][128];
    __shared__ float Xs[16][132];

    const float* Mp = ws + WS_M_OFF + (size_t)b * 128 * 128;

    const int rg = t >> 4;         // 0..15 -> rows rg*8..+7
    const int cg = t & 15;         // 0..15 -> cols c0..+3 and 64+c0..+3
    const int r0 = rg * 8;
    const int c0 = cg * 4;

    float acc[8][8];
#pragma unroll
    for (int j = 0; j < 8; ++j)
#pragma unroll
        for (int i = 0; i < 8; ++i) acc[j][i] = 0.f;

    for (int kt = 0; kt < 8; ++kt) {
        const int k0 = kt * 16;
        // stage Ms[kk][r]
        {
            const int r   = t & 127;
            const int kk0 = (t >> 7) * 8;
            const float* src = Mp + r * 128 + k0 + kk0;
            float4 a0 = *(const float4*)src;
            float4 a1 = *(const float4*)(src + 4);
            Ms[kk0 + 0][r] = a0.x; Ms[kk0 + 1][r] = a0.y; Ms[kk0 + 2][r] = a0.z; Ms[kk0 + 3][r] = a0.w;
            Ms[kk0 + 4][r] = a1.x; Ms[kk0 + 5][r] = a1.y; Ms[kk0 + 6][r] = a1.z; Ms[kk0 + 7][r] = a1.w;
        }
        // stage Xs[kk][n]
        {
            const int kk = t >> 4;
            const int nq = (t & 15) * 8;
            const float* src = x + (size_t)(b * NCH + k0 + kk) * NPIX + n0 + nq;
            *(float4*)&Xs[kk][nq]     = *(const float4*)src;
            *(float4*)&Xs[kk][nq + 4] = *(const float4*)(src + 4);
        }
        __syncthreads();
#pragma unroll
        for (int kk = 0; kk < 16; ++kk) {
            float m[8], xv[8];
            *(float4*)&m[0]  = *(const float4*)&Ms[kk][r0];
            *(float4*)&m[4]  = *(const float4*)&Ms[kk][r0 + 4];
            *(float4*)&xv[0] = *(const float4*)&Xs[kk][c0];
            *(float4*)&xv[4] = *(const float4*)&Xs[kk][64 + c0];
#pragma unroll
            for (int j = 0; j < 8; ++j)
#pragma unroll
                for (int i = 0; i < 8; ++i) acc[j][i] = fmaf(m[j], xv[i], acc[j][i]);
        }
        __syncthreads();
    }

#pragma unroll
    for (int j = 0; j < 8; ++j) {
        const float bj = bias[r0 + j];
        float* dst = y + (size_t)(b * 128 + r0 + j) * NPIX + n0;
        *(float4*)(dst + c0)      = make_float4(acc[j][0] + bj, acc[j][1] + bj, acc[j][2] + bj, acc[j][3] + bj);
        *(float4*)(dst + 64 + c0) = make_float4(acc[j][4] + bj, acc[j][5] + bj, acc[j][6] + bj, acc[j][7] + bj);
    }
}

extern "C" void kernel_launch(void* const* d_in, const int* in_sizes, int n_in,
                              void* d_out, int out_size, void* d_ws, size_t ws_size,
                              hipStream_t stream) {
    (void)in_sizes; (void)n_in; (void)out_size; (void)ws_size;
    const float* x     = (const float*)d_in[0];
    const float* w_qkv = (const float*)d_in[1];
    const float* w_out = (const float*)d_in[2];
    const float* b_out = (const float*)d_in[3];
    float* y  = (float*)d_out;
    float* ws = (float*)d_ws;

    // zero the atomic accumulator region (ws is re-poisoned before every call)
    hipMemsetAsync(d_ws, 0, WS_ZERO_BYTES, stream);

    k1_partials<<<dim3(32, NBATCH),         256, 0, stream>>>(x, w_qkv, ws);
    k2_mprime  <<<dim3(NBATCH, 4),          256, 0, stream>>>(w_qkv, w_out, ws);
    k3_out     <<<dim3(NPIX / 128, NBATCH), 256, 0, stream>>>(x, b_out, ws, y);
}

// Round 3
// 324.852 us; speedup vs baseline: 2.2876x; 2.2640x over previous
//
#include <hip/hip_runtime.h>
#include <cmath>

// Problem constants
#define NBATCH 16
#define NCH    128      // C = channels = HIDDEN
#define NPIX   16384    // H*W
#define NREP   2        // atomic replica slots

// Workspace layout
//   floats: Spart [16][NREP][128] ; Apart [16][NREP][4][32][32]
//   then bf16 Mbf [16][128][128]
#define WS_S_OFF 0
#define WS_A_OFF (NBATCH * NREP * 128)
#define WS_ZERO_FLOATS (WS_A_OFF + NBATCH * NREP * 4096)
#define WS_MBF_BYTE ((size_t)WS_ZERO_FLOATS * 4)

typedef __bf16 bf16x8 __attribute__((ext_vector_type(8)));
typedef __bf16 bf16x4 __attribute__((ext_vector_type(4)));
typedef __bf16 bf16x2 __attribute__((ext_vector_type(2)));
typedef float  f32x4  __attribute__((ext_vector_type(4)));

#define MFMA16(a, b, c) __builtin_amdgcn_mfma_f32_16x16x32_bf16((a), (b), (c), 0, 0, 0)

// ---------------------------------------------------------------------------
// K1: 512 blocks = (32 n-groups) x (16 batches), 8 chunks of 64 pixels each.
// Per chunk: KV = Wkv @ X via MFMA (wave w owns head w: 32 k-rows + 32 v-rows),
// exp on k-rows in-register, E/V -> LDS (A-operand layout), A_h += E_h V_h^T
// via MFMA (same-wave LDS, no barrier). S in registers. Atomics at epilogue.
// ---------------------------------------------------------------------------
__global__ __launch_bounds__(256, 2) void k1_partials(const float* __restrict__ x,
                                                      const float* __restrict__ w_qkv,
                                                      float* __restrict__ ws)
{
    const int b = blockIdx.y;
    const int g = blockIdx.x;           // 0..31
    const int t = threadIdx.x;
    const int w = t >> 6;               // wave == head
    const int l = t & 63;
    const int lm = l & 15;              // MFMA m/n/col lane index
    const int q  = l >> 4;              // quad

    __shared__ __align__(16) __bf16 Xs[64][136];   // [pix][ch], stride 272 B (uniform-8 banks for b128 reads)
    __shared__ __align__(16) __bf16 EVs[256][72];  // rows 0-127: E = exp(k); 128-255: V

    // W fragments (MFMA A-operand), loaded once per block, fp32 -> bf16 in-register.
    // rt 0,1: k-rows of head w; rt 2,3: v-rows of head w (wkv row space).
    const float* wkv = w_qkv + 128 * NCH;
    bf16x8 wfrag[4][4];   // [rt][ks]
#pragma unroll
    for (int rt = 0; rt < 4; ++rt) {
        const int row = (rt < 2) ? (w * 32 + rt * 16 + lm)
                                 : (128 + w * 32 + (rt - 2) * 16 + lm);
#pragma unroll
        for (int ks = 0; ks < 4; ++ks) {
            const float* src = wkv + row * NCH + ks * 32 + q * 8;
            float4 p0 = *(const float4*)src;
            float4 p1 = *(const float4*)(src + 4);
            bf16x8 f;
            f[0] = (__bf16)p0.x; f[1] = (__bf16)p0.y; f[2] = (__bf16)p0.z; f[3] = (__bf16)p0.w;
            f[4] = (__bf16)p1.x; f[5] = (__bf16)p1.y; f[6] = (__bf16)p1.z; f[7] = (__bf16)p1.w;
            wfrag[rt][ks] = f;
        }
    }

    f32x4 a_acc[2][2];                 // A_h accumulator (persists across chunks)
#pragma unroll
    for (int dt = 0; dt < 2; ++dt)
#pragma unroll
        for (int et = 0; et < 2; ++et) a_acc[dt][et] = (f32x4)0.f;
    float s8[8];                       // S col-partials (rows rt*16+q*4+r, col class lm)
#pragma unroll
    for (int j = 0; j < 8; ++j) s8[j] = 0.f;

    for (int ci = 0; ci < 8; ++ci) {
        const int n0 = (g + ci * 32) * 64;

        // ---- stage X chunk (wave w: ch rows [w*32, w*32+32)), coalesced dword loads,
        //      packed bf16x4 (b64) LDS writes
#pragma unroll
        for (int rq = 0; rq < 8; ++rq) {
            const int r0 = w * 32 + rq * 4;
            const float* xb = x + (size_t)(b * NCH + r0) * NPIX + n0 + l;
            float f0 = xb[0];
            float f1 = xb[NPIX];
            float f2 = xb[2 * NPIX];
            float f3 = xb[3 * NPIX];
            bf16x4 pk;
            pk[0] = (__bf16)f0; pk[1] = (__bf16)f1; pk[2] = (__bf16)f2; pk[3] = (__bf16)f3;
            *(bf16x4*)&Xs[l][r0] = pk;
        }
        __syncthreads();

        // ---- KV GEMM: 64 rows (head w's k+v) x 64 pixels, K=128
        f32x4 acc[4][4];
#pragma unroll
        for (int rt = 0; rt < 4; ++rt)
#pragma unroll
            for (int ct = 0; ct < 4; ++ct) acc[rt][ct] = (f32x4)0.f;

#pragma unroll
        for (int ks = 0; ks < 4; ++ks) {
            bf16x8 bf[4];
#pragma unroll
            for (int ct = 0; ct < 4; ++ct)
                bf[ct] = *(const bf16x8*)&Xs[ct * 16 + lm][ks * 32 + q * 8];
#pragma unroll
            for (int rt = 0; rt < 4; ++rt)
#pragma unroll
                for (int ct = 0; ct < 4; ++ct)
                    acc[rt][ct] = MFMA16(wfrag[rt][ks], bf[ct], acc[rt][ct]);
        }

        // ---- exp on k-rows + S partials + E/V -> LDS (pair-packed b32, conflict-free)
#pragma unroll
        for (int rt = 0; rt < 4; ++rt) {
            const int rowbase = (rt < 2) ? (w * 32 + rt * 16)
                                         : (128 + w * 32 + (rt - 2) * 16);
#pragma unroll
            for (int ct = 0; ct < 4; ++ct) {
                f32x4 v = acc[rt][ct];
                if (rt < 2) {
#pragma unroll
                    for (int r = 0; r < 4; ++r) {
                        float e = __expf(v[r]);
                        v[r] = e;
                        s8[rt * 4 + r] += e;
                    }
                }
                const int colw = ct * 16 + (lm & ~1);
#pragma unroll
                for (int s = 0; s < 2; ++s) {
                    float fe = v[2 * s];
                    float fo = v[2 * s + 1];
                    float ge = __shfl_xor(fe, 1);
                    float go = __shfl_xor(fo, 1);
                    bf16x2 pw;
                    if (l & 1) { pw[0] = (__bf16)go; pw[1] = (__bf16)fo; }
                    else       { pw[0] = (__bf16)fe; pw[1] = (__bf16)ge; }
                    const int roww = rowbase + q * 4 + 2 * s + (l & 1);
                    *(bf16x2*)&EVs[roww][colw] = pw;
                }
            }
        }

        // ---- A-phase: A_w += E_w * V_w^T (K = 64 chunk pixels); same-wave LDS,
        //      compiler's lgkmcnt handles the write->read dependency (no barrier).
#pragma unroll
        for (int ks2 = 0; ks2 < 2; ++ks2) {
            bf16x8 ea[2], vb[2];
#pragma unroll
            for (int dt = 0; dt < 2; ++dt)
                ea[dt] = *(const bf16x8*)&EVs[w * 32 + dt * 16 + lm][ks2 * 32 + q * 8];
#pragma unroll
            for (int et = 0; et < 2; ++et)
                vb[et] = *(const bf16x8*)&EVs[128 + w * 32 + et * 16 + lm][ks2 * 32 + q * 8];
#pragma unroll
            for (int dt = 0; dt < 2; ++dt)
#pragma unroll
                for (int et = 0; et < 2; ++et)
                    a_acc[dt][et] = MFMA16(ea[dt], vb[et], a_acc[dt][et]);
        }
        __syncthreads();   // protect Xs from next chunk's staging
    }

    // ---- epilogue: atomics to replica slot
    const int rep = g & (NREP - 1);

#pragma unroll
    for (int j = 0; j < 8; ++j) {
        float v = s8[j];
        v += __shfl_xor(v, 1);
        v += __shfl_xor(v, 2);
        v += __shfl_xor(v, 4);
        v += __shfl_xor(v, 8);
        s8[j] = v;
    }
    if (lm == 0) {
        float* Sp = ws + WS_S_OFF + (size_t)(b * NREP + rep) * 128;
#pragma unroll
        for (int rt2 = 0; rt2 < 2; ++rt2)
#pragma unroll
            for (int r = 0; r < 4; ++r)
                atomicAdd(&Sp[w * 32 + rt2 * 16 + q * 4 + r], s8[rt2 * 4 + r]);
    }
    {
        float* Ab = ws + WS_A_OFF + (size_t)((b * NREP + rep) * 4 + w) * 1024;
#pragma unroll
        for (int dt = 0; dt < 2; ++dt)
#pragma unroll
            for (int et = 0; et < 2; ++et)
#pragma unroll
                for (int r = 0; r < 4; ++r)
                    atomicAdd(&Ab[(dt * 16 + q * 4 + r) * 32 + et * 16 + lm],
                              a_acc[dt][et][r]);
    }
}

// ---------------------------------------------------------------------------
// K2: reduce replicas; ctx = A/S; T = w_out*ctx; M' = scale*T*Wq (fp32),
//     written out as bf16 for K3's MFMA.
// ---------------------------------------------------------------------------
__global__ __launch_bounds__(256) void k2_mprime(const float* __restrict__ w_qkv,
                                                 const float* __restrict__ w_out,
                                                 const float* __restrict__ ws,
                                                 __bf16* __restrict__ Mbf)
{
    const int b  = blockIdx.x;
    const int o0 = blockIdx.y * 32;
    const int t  = threadIdx.x;

    __shared__ float ctx[4][32][32];  // [h][d][e]
    __shared__ float Ts[32][128];     // [oo][hd]
    __shared__ float Wqs[32][128];    // Wq slab
    __shared__ float Ss[128];

    if (t < 128) {
        float s = 0.f;
#pragma unroll
        for (int r = 0; r < NREP; ++r)
            s += ws[WS_S_OFF + (size_t)(b * NREP + r) * 128 + t];
        Ss[t] = s;
    }
    __syncthreads();

    for (int i = t; i < 4096; i += 256) {
        float a = 0.f;
#pragma unroll
        for (int r = 0; r < NREP; ++r)
            a += ws[WS_A_OFF + (size_t)(b * NREP + r) * 4096 + i];
        const int hh = i >> 10, d = (i >> 5) & 31, e = i & 31;
        ctx[hh][d][e] = a / Ss[hh * 32 + d];
    }
    __syncthreads();

    // T rows for this o-slab
    {
        const int oo  = t >> 3;
        const int o   = o0 + oo;
        const int hd0 = (t & 7) * 16;
        const int hh  = hd0 >> 5;
        const int db  = hd0 & 31;
        float wo[32];
#pragma unroll
        for (int e4 = 0; e4 < 32; e4 += 4)
            *(float4*)&wo[e4] = *(const float4*)&w_out[o * NCH + hh * 32 + e4];
#pragma unroll
        for (int k = 0; k < 16; ++k) {
            const int d = db + k;
            float s = 0.f;
#pragma unroll
            for (int e = 0; e < 32; ++e) s = fmaf(wo[e], ctx[hh][d][e], s);
            Ts[oo][hd0 + k] = s;
        }
    }
    __syncthreads();

    float macc[16];
#pragma unroll
    for (int ii = 0; ii < 16; ++ii) macc[ii] = 0.f;

    for (int slab = 0; slab < 4; ++slab) {
        for (int i = t; i < 32 * 128; i += 256)
            Wqs[i >> 7][i & 127] = w_qkv[(size_t)(slab * 32 + (i >> 7)) * NCH + (i & 127)];
        __syncthreads();
#pragma unroll
        for (int ii = 0; ii < 16; ++ii) {
            const int i  = t + ii * 256;
            const int oo = i >> 7;
            const int c  = i & 127;
            float s = macc[ii];
#pragma unroll
            for (int k = 0; k < 32; ++k)
                s = fmaf(Ts[oo][slab * 32 + k], Wqs[k][c], s);
            macc[ii] = s;
        }
        __syncthreads();
    }

    const float scale = 0.17677669529663687f;  // 32^-0.5
#pragma unroll
    for (int ii = 0; ii < 16; ++ii) {
        const int i  = t + ii * 256;
        const int oo = i >> 7;
        const int c  = i & 127;
        Mbf[(size_t)(b * NCH + o0 + oo) * NCH + c] = (__bf16)(macc[ii] * scale);
    }
}

// ---------------------------------------------------------------------------
// K3: y[b] = M'[b] @ X[b] + bias via MFMA. Block tile: 128 rows x 128 pixels.
// ---------------------------------------------------------------------------
__global__ __launch_bounds__(256, 2) void k3_out(const float* __restrict__ x,
                                                 const float* __restrict__ bias,
                                                 const __bf16* __restrict__ Mbf,
                                                 float* __restrict__ y)
{
    const int b  = blockIdx.y;
    const int n0 = blockIdx.x * 128;
    const int t  = threadIdx.x;
    const int w  = t >> 6, l = t & 63;
    const int lm = l & 15, q = l >> 4;
    const int rw = (w & 1) * 64;    // wave row base
    const int pw = (w >> 1) * 64;   // wave pixel base (within tile)

    __shared__ __align__(16) __bf16 Xs[128][136];

    // M' fragments (A-operand) from bf16 M', L2-resident
    const __bf16* Mb = Mbf + (size_t)b * NCH * NCH;
    bf16x8 mfrag[4][4];
#pragma unroll
    for (int rt = 0; rt < 4; ++rt)
#pragma unroll
        for (int ks = 0; ks < 4; ++ks)
            mfrag[rt][ks] = *(const bf16x8*)&Mb[(size_t)(rw + rt * 16 + lm) * NCH + ks * 32 + q * 8];

    // stage X tile (wave w: ch rows [w*32, w*32+32), two 64-pixel halves)
#pragma unroll
    for (int rq = 0; rq < 8; ++rq) {
        const int r0 = w * 32 + rq * 4;
        const float* xb = x + (size_t)(b * NCH + r0) * NPIX + n0;
        {
            float f0 = xb[l], f1 = xb[NPIX + l], f2 = xb[2 * NPIX + l], f3 = xb[3 * NPIX + l];
            bf16x4 pk;
            pk[0] = (__bf16)f0; pk[1] = (__bf16)f1; pk[2] = (__bf16)f2; pk[3] = (__bf16)f3;
            *(bf16x4*)&Xs[l][r0] = pk;
        }
        {
            float f0 = xb[64 + l], f1 = xb[NPIX + 64 + l], f2 = xb[2 * NPIX + 64 + l], f3 = xb[3 * NPIX + 64 + l];
            bf16x4 pk;
            pk[0] = (__bf16)f0; pk[1] = (__bf16)f1; pk[2] = (__bf16)f2; pk[3] = (__bf16)f3;
            *(bf16x4*)&Xs[64 + l][r0] = pk;
        }
    }
    __syncthreads();

    f32x4 acc[4][4];
#pragma unroll
    for (int rt = 0; rt < 4; ++rt)
#pragma unroll
        for (int ct = 0; ct < 4; ++ct) acc[rt][ct] = (f32x4)0.f;

#pragma unroll
    for (int ks = 0; ks < 4; ++ks) {
        bf16x8 bf[4];
#pragma unroll
        for (int ct = 0; ct < 4; ++ct)
            bf[ct] = *(const bf16x8*)&Xs[pw + ct * 16 + lm][ks * 32 + q * 8];
#pragma unroll
        for (int rt = 0; rt < 4; ++rt)
#pragma unroll
            for (int ct = 0; ct < 4; ++ct)
                acc[rt][ct] = MFMA16(mfrag[rt][ks], bf[ct], acc[rt][ct]);
    }

#pragma unroll
    for (int rt = 0; rt < 4; ++rt) {
#pragma unroll
        for (int r = 0; r < 4; ++r) {
            const int row = rw + rt * 16 + q * 4 + r;
            const float bb = bias[row];
            float* yp = y + (size_t)(b * NCH + row) * NPIX + n0 + pw + lm;
#pragma unroll
            for (int ct = 0; ct < 4; ++ct)
                yp[ct * 16] = acc[rt][ct][r] + bb;
        }
    }
}

extern "C" void kernel_launch(void* const* d_in, const int* in_sizes, int n_in,
                              void* d_out, int out_size, void* d_ws, size_t ws_size,
                              hipStream_t stream) {
    (void)in_sizes; (void)n_in; (void)out_size; (void)ws_size;
    const float* x     = (const float*)d_in[0];
    const float* w_qkv = (const float*)d_in[1];
    const float* w_out = (const float*)d_in[2];
    const float* b_out = (const float*)d_in[3];
    float*  y   = (float*)d_out;
    float*  ws  = (float*)d_ws;
    __bf16* Mbf = (__bf16*)((char*)d_ws + WS_MBF_BYTE);

    // zero the atomic accumulator region (ws is re-poisoned before every call)
    hipMemsetAsync(d_ws, 0, (size_t)WS_ZERO_FLOATS * 4, stream);

    k1_partials<<<dim3(32, NBATCH),         256, 0, stream>>>(x, w_qkv, ws);
    k2_mprime  <<<dim3(NBATCH, 4),          256, 0, stream>>>(w_qkv, w_out, ws, Mbf);
    k3_out     <<<dim3(NPIX / 128, NBATCH), 256, 0, stream>>>(x, b_out, Mbf, y);
}

// Round 4
// 322.995 us; speedup vs baseline: 2.3008x; 1.0057x over previous
//
#include <hip/hip_runtime.h>
#include <cmath>

// Problem constants
#define NBATCH 16
#define NCH    128      // C = channels = HIDDEN
#define NPIX   16384    // H*W
#define NREP   2        // atomic replica slots

// Workspace layout
//   floats: Spart [16][NREP][128] ; Apart [16][NREP][4][32][32]
//   then bf16 Mbf [16][128][128]
#define WS_S_OFF 0
#define WS_A_OFF (NBATCH * NREP * 128)
#define WS_ZERO_FLOATS (WS_A_OFF + NBATCH * NREP * 4096)
#define WS_MBF_BYTE ((size_t)WS_ZERO_FLOATS * 4)

typedef __bf16 bf16x8 __attribute__((ext_vector_type(8)));
typedef __bf16 bf16x4 __attribute__((ext_vector_type(4)));
typedef __bf16 bf16x2 __attribute__((ext_vector_type(2)));
typedef float  f32x4  __attribute__((ext_vector_type(4)));

#define MFMA16(a, b, c) __builtin_amdgcn_mfma_f32_16x16x32_bf16((a), (b), (c), 0, 0, 0)

// Barrier without the compiler's vmcnt(0) drain: LDS-only fence + s_barrier.
// Keeps prefetch global_loads (to VGPRs) in flight across the barrier.
__device__ __forceinline__ void barrier_lds() {
    asm volatile("s_waitcnt lgkmcnt(0)\n\ts_barrier" ::: "memory");
}

// ---------------------------------------------------------------------------
// K1: 512 blocks = (32 n-groups) x (16 batches), 8 chunks of 64 pixels each.
// Per chunk: KV = Wkv @ X via MFMA (wave w owns head w), exp on k-rows,
// E/V spilled 32-px at a time to wave-private LDS rows (no barrier), A_h
// accumulated via MFMA. X loads for chunk i+1 prefetched into registers
// during chunk i's compute (lds-only barriers keep them in flight).
// ---------------------------------------------------------------------------
__global__ __launch_bounds__(256, 2) void k1_partials(const float* __restrict__ x,
                                                      const float* __restrict__ w_qkv,
                                                      float* __restrict__ ws)
{
    const int b = blockIdx.y;
    const int g = blockIdx.x;           // 0..31
    const int t = threadIdx.x;
    const int w = t >> 6;               // wave == head
    const int l = t & 63;
    const int lm = l & 15;              // MFMA m/n/col lane index
    const int q  = l >> 4;              // quad

    __shared__ __align__(16) __bf16 Xs[64][136];   // [pix][ch] (17.0 KB)
    __shared__ __align__(16) __bf16 EVs[256][40];  // 32-px sub-chunk: E rows 0-127, V 128-255 (20 KB)

    // W fragments (MFMA A-operand), loaded once, fp32 -> bf16 in-register.
    const float* wkv = w_qkv + 128 * NCH;
    bf16x8 wfrag[4][4];   // [rt][ks]; rt 0,1 = k-rows of head w, rt 2,3 = v-rows
#pragma unroll
    for (int rt = 0; rt < 4; ++rt) {
        const int row = (rt < 2) ? (w * 32 + rt * 16 + lm)
                                 : (128 + w * 32 + (rt - 2) * 16 + lm);
#pragma unroll
        for (int ks = 0; ks < 4; ++ks) {
            const float* src = wkv + row * NCH + ks * 32 + q * 8;
            float4 p0 = *(const float4*)src;
            float4 p1 = *(const float4*)(src + 4);
            bf16x8 f;
            f[0] = (__bf16)p0.x; f[1] = (__bf16)p0.y; f[2] = (__bf16)p0.z; f[3] = (__bf16)p0.w;
            f[4] = (__bf16)p1.x; f[5] = (__bf16)p1.y; f[6] = (__bf16)p1.z; f[7] = (__bf16)p1.w;
            wfrag[rt][ks] = f;
        }
    }

    f32x4 a_acc[2][2];                 // A_h accumulator (persists across chunks)
#pragma unroll
    for (int dt = 0; dt < 2; ++dt)
#pragma unroll
        for (int et = 0; et < 2; ++et) a_acc[dt][et] = (f32x4)0.f;
    float s8[8];                       // S partials
#pragma unroll
    for (int j = 0; j < 8; ++j) s8[j] = 0.f;

    // prefetch registers: wave w stages ch rows [w*32, w*32+32) for 64 px
    float fx[8][4];
    const float* xbase = x + (size_t)(b * NCH + w * 32) * NPIX + l;

    // issue loads for chunk 0
    {
        const int n0 = g * 64;
#pragma unroll
        for (int rq = 0; rq < 8; ++rq) {
            const float* xb = xbase + (size_t)(rq * 4) * NPIX + n0;
            fx[rq][0] = xb[0];
            fx[rq][1] = xb[NPIX];
            fx[rq][2] = xb[2 * NPIX];
            fx[rq][3] = xb[3 * NPIX];
        }
    }

    for (int ci = 0; ci < 8; ++ci) {
        // ---- cvt + write staged chunk to Xs (Xs writable: bar2 of prev iter)
#pragma unroll
        for (int rq = 0; rq < 8; ++rq) {
            bf16x4 pk;
            pk[0] = (__bf16)fx[rq][0]; pk[1] = (__bf16)fx[rq][1];
            pk[2] = (__bf16)fx[rq][2]; pk[3] = (__bf16)fx[rq][3];
            *(bf16x4*)&Xs[l][w * 32 + rq * 4] = pk;
        }
        // ---- issue prefetch for chunk ci+1 (stays in flight across barriers)
        if (ci < 7) {
            const int n0 = (g + (ci + 1) * 32) * 64;
#pragma unroll
            for (int rq = 0; rq < 8; ++rq) {
                const float* xb = xbase + (size_t)(rq * 4) * NPIX + n0;
                fx[rq][0] = xb[0];
                fx[rq][1] = xb[NPIX];
                fx[rq][2] = xb[2 * NPIX];
                fx[rq][3] = xb[3 * NPIX];
            }
        }
        barrier_lds();   // Xs ready

        // ---- KV GEMM: 64 rows (head w's k+v) x 64 pixels, K=128
        f32x4 acc[4][4];
#pragma unroll
        for (int rt = 0; rt < 4; ++rt)
#pragma unroll
            for (int ct = 0; ct < 4; ++ct) acc[rt][ct] = (f32x4)0.f;

#pragma unroll
        for (int ks = 0; ks < 4; ++ks) {
            bf16x8 bf[4];
#pragma unroll
            for (int ct = 0; ct < 4; ++ct)
                bf[ct] = *(const bf16x8*)&Xs[ct * 16 + lm][ks * 32 + q * 8];
#pragma unroll
            for (int rt = 0; rt < 4; ++rt)
#pragma unroll
                for (int ct = 0; ct < 4; ++ct)
                    acc[rt][ct] = MFMA16(wfrag[rt][ks], bf[ct], acc[rt][ct]);
        }

        // ---- exp + S + spill E/V in two 32-px halves (wave-private EVs rows,
        //      no barrier), each followed by A-phase MFMA (K=32)
#pragma unroll
        for (int hf = 0; hf < 2; ++hf) {
#pragma unroll
            for (int rt = 0; rt < 4; ++rt) {
                const int rowbase = (rt < 2) ? (w * 32 + rt * 16)
                                             : (128 + w * 32 + (rt - 2) * 16);
#pragma unroll
                for (int c2 = 0; c2 < 2; ++c2) {
                    const int ct = hf * 2 + c2;
                    f32x4 v = acc[rt][ct];
                    if (rt < 2) {
#pragma unroll
                        for (int r = 0; r < 4; ++r) {
                            float e = __expf(v[r]);
                            v[r] = e;
                            s8[rt * 4 + r] += e;
                        }
                    }
                    const int colw = c2 * 16 + (lm & ~1);
#pragma unroll
                    for (int s = 0; s < 2; ++s) {
                        float fe = v[2 * s];
                        float fo = v[2 * s + 1];
                        float ge = __shfl_xor(fe, 1);
                        float go = __shfl_xor(fo, 1);
                        bf16x2 pw;
                        if (l & 1) { pw[0] = (__bf16)go; pw[1] = (__bf16)fo; }
                        else       { pw[0] = (__bf16)fe; pw[1] = (__bf16)ge; }
                        const int roww = rowbase + q * 4 + 2 * s + (l & 1);
                        *(bf16x2*)&EVs[roww][colw] = pw;
                    }
                }
            }
            // A-phase for this 32-px half (same-wave LDS; compiler waits lgkmcnt)
            {
                bf16x8 ea[2], vb[2];
#pragma unroll
                for (int dt = 0; dt < 2; ++dt)
                    ea[dt] = *(const bf16x8*)&EVs[w * 32 + dt * 16 + lm][q * 8];
#pragma unroll
                for (int et = 0; et < 2; ++et)
                    vb[et] = *(const bf16x8*)&EVs[128 + w * 32 + et * 16 + lm][q * 8];
#pragma unroll
                for (int dt = 0; dt < 2; ++dt)
#pragma unroll
                    for (int et = 0; et < 2; ++et)
                        a_acc[dt][et] = MFMA16(ea[dt], vb[et], a_acc[dt][et]);
            }
        }
        barrier_lds();   // Xs consumed by all waves; safe to restage
    }

    // ---- epilogue: atomics to replica slot
    const int rep = g & (NREP - 1);

#pragma unroll
    for (int j = 0; j < 8; ++j) {
        float v = s8[j];
        v += __shfl_xor(v, 1);
        v += __shfl_xor(v, 2);
        v += __shfl_xor(v, 4);
        v += __shfl_xor(v, 8);
        s8[j] = v;
    }
    if (lm == 0) {
        float* Sp = ws + WS_S_OFF + (size_t)(b * NREP + rep) * 128;
#pragma unroll
        for (int rt2 = 0; rt2 < 2; ++rt2)
#pragma unroll
            for (int r = 0; r < 4; ++r)
                atomicAdd(&Sp[w * 32 + rt2 * 16 + q * 4 + r], s8[rt2 * 4 + r]);
    }
    {
        float* Ab = ws + WS_A_OFF + (size_t)((b * NREP + rep) * 4 + w) * 1024;
#pragma unroll
        for (int dt = 0; dt < 2; ++dt)
#pragma unroll
            for (int et = 0; et < 2; ++et)
#pragma unroll
                for (int r = 0; r < 4; ++r)
                    atomicAdd(&Ab[(dt * 16 + q * 4 + r) * 32 + et * 16 + lm],
                              a_acc[dt][et][r]);
    }
}

// ---------------------------------------------------------------------------
// K2: reduce replicas; ctx = A/S; T = w_out*ctx; M' = scale*T*Wq (fp32),
//     written out as bf16 for K3's MFMA.
// ---------------------------------------------------------------------------
__global__ __launch_bounds__(256) void k2_mprime(const float* __restrict__ w_qkv,
                                                 const float* __restrict__ w_out,
                                                 const float* __restrict__ ws,
                                                 __bf16* __restrict__ Mbf)
{
    const int b  = blockIdx.x;
    const int o0 = blockIdx.y * 32;
    const int t  = threadIdx.x;

    __shared__ float ctx[4][32][32];  // [h][d][e]
    __shared__ float Ts[32][128];     // [oo][hd]
    __shared__ float Wqs[32][128];    // Wq slab
    __shared__ float Ss[128];

    if (t < 128) {
        float s = 0.f;
#pragma unroll
        for (int r = 0; r < NREP; ++r)
            s += ws[WS_S_OFF + (size_t)(b * NREP + r) * 128 + t];
        Ss[t] = s;
    }
    __syncthreads();

    for (int i = t; i < 4096; i += 256) {
        float a = 0.f;
#pragma unroll
        for (int r = 0; r < NREP; ++r)
            a += ws[WS_A_OFF + (size_t)(b * NREP + r) * 4096 + i];
        const int hh = i >> 10, d = (i >> 5) & 31, e = i & 31;
        ctx[hh][d][e] = a / Ss[hh * 32 + d];
    }
    __syncthreads();

    // T rows for this o-slab
    {
        const int oo  = t >> 3;
        const int o   = o0 + oo;
        const int hd0 = (t & 7) * 16;
        const int hh  = hd0 >> 5;
        const int db  = hd0 & 31;
        float wo[32];
#pragma unroll
        for (int e4 = 0; e4 < 32; e4 += 4)
            *(float4*)&wo[e4] = *(const float4*)&w_out[o * NCH + hh * 32 + e4];
#pragma unroll
        for (int k = 0; k < 16; ++k) {
            const int d = db + k;
            float s = 0.f;
#pragma unroll
            for (int e = 0; e < 32; ++e) s = fmaf(wo[e], ctx[hh][d][e], s);
            Ts[oo][hd0 + k] = s;
        }
    }
    __syncthreads();

    float macc[16];
#pragma unroll
    for (int ii = 0; ii < 16; ++ii) macc[ii] = 0.f;

    for (int slab = 0; slab < 4; ++slab) {
        for (int i = t; i < 32 * 128; i += 256)
            Wqs[i >> 7][i & 127] = w_qkv[(size_t)(slab * 32 + (i >> 7)) * NCH + (i & 127)];
        __syncthreads();
#pragma unroll
        for (int ii = 0; ii < 16; ++ii) {
            const int i  = t + ii * 256;
            const int oo = i >> 7;
            const int c  = i & 127;
            float s = macc[ii];
#pragma unroll
            for (int k = 0; k < 32; ++k)
                s = fmaf(Ts[oo][slab * 32 + k], Wqs[k][c], s);
            macc[ii] = s;
        }
        __syncthreads();
    }

    const float scale = 0.17677669529663687f;  // 32^-0.5
#pragma unroll
    for (int ii = 0; ii < 16; ++ii) {
        const int i  = t + ii * 256;
        const int oo = i >> 7;
        const int c  = i & 127;
        Mbf[(size_t)(b * NCH + o0 + oo) * NCH + c] = (__bf16)(macc[ii] * scale);
    }
}

// ---------------------------------------------------------------------------
// K3: y[b] = M'[b] @ X[b] + bias via MFMA. Block tile: 128 rows x 64 pixels,
// wave tile 32 rows x 64 px (mfrag 32 + acc 32 regs -> 4 blocks/CU).
// ---------------------------------------------------------------------------
__global__ __launch_bounds__(256, 4) void k3_out(const float* __restrict__ x,
                                                 const float* __restrict__ bias,
                                                 const __bf16* __restrict__ Mbf,
                                                 float* __restrict__ y)
{
    const int b  = blockIdx.y;
    const int n0 = blockIdx.x * 64;
    const int t  = threadIdx.x;
    const int w  = t >> 6, l = t & 63;
    const int lm = l & 15, q = l >> 4;

    __shared__ __align__(16) __bf16 Xs[64][136];

    // M' fragments (A-operand): wave w owns rows [w*32, w*32+32)
    const __bf16* Mb = Mbf + (size_t)b * NCH * NCH;
    bf16x8 mfrag[2][4];
#pragma unroll
    for (int rt = 0; rt < 2; ++rt)
#pragma unroll
        for (int ks = 0; ks < 4; ++ks)
            mfrag[rt][ks] = *(const bf16x8*)&Mb[(size_t)(w * 32 + rt * 16 + lm) * NCH + ks * 32 + q * 8];

    // stage X tile: wave w stages ch rows [w*32, w*32+32) for the 64 px
#pragma unroll
    for (int rq = 0; rq < 8; ++rq) {
        const int r0 = w * 32 + rq * 4;
        const float* xb = x + (size_t)(b * NCH + r0) * NPIX + n0 + l;
        float f0 = xb[0], f1 = xb[NPIX], f2 = xb[2 * NPIX], f3 = xb[3 * NPIX];
        bf16x4 pk;
        pk[0] = (__bf16)f0; pk[1] = (__bf16)f1; pk[2] = (__bf16)f2; pk[3] = (__bf16)f3;
        *(bf16x4*)&Xs[l][r0] = pk;
    }
    __syncthreads();

    f32x4 acc[2][4];
#pragma unroll
    for (int rt = 0; rt < 2; ++rt)
#pragma unroll
        for (int ct = 0; ct < 4; ++ct) acc[rt][ct] = (f32x4)0.f;

#pragma unroll
    for (int ks = 0; ks < 4; ++ks) {
        bf16x8 bf[4];
#pragma unroll
        for (int ct = 0; ct < 4; ++ct)
            bf[ct] = *(const bf16x8*)&Xs[ct * 16 + lm][ks * 32 + q * 8];
#pragma unroll
        for (int rt = 0; rt < 2; ++rt)
#pragma unroll
            for (int ct = 0; ct < 4; ++ct)
                acc[rt][ct] = MFMA16(mfrag[rt][ks], bf[ct], acc[rt][ct]);
    }

#pragma unroll
    for (int rt = 0; rt < 2; ++rt) {
#pragma unroll
        for (int r = 0; r < 4; ++r) {
            const int row = w * 32 + rt * 16 + q * 4 + r;
            const float bb = bias[row];
            float* yp = y + (size_t)(b * NCH + row) * NPIX + n0 + lm;
#pragma unroll
            for (int ct = 0; ct < 4; ++ct)
                yp[ct * 16] = acc[rt][ct][r] + bb;
        }
    }
}

extern "C" void kernel_launch(void* const* d_in, const int* in_sizes, int n_in,
                              void* d_out, int out_size, void* d_ws, size_t ws_size,
                              hipStream_t stream) {
    (void)in_sizes; (void)n_in; (void)out_size; (void)ws_size;
    const float* x     = (const float*)d_in[0];
    const float* w_qkv = (const float*)d_in[1];
    const float* w_out = (const float*)d_in[2];
    const float* b_out = (const float*)d_in[3];
    float*  y   = (float*)d_out;
    float*  ws  = (float*)d_ws;
    __bf16* Mbf = (__bf16*)((char*)d_ws + WS_MBF_BYTE);

    // zero the atomic accumulator region (ws is re-poisoned before every call)
    hipMemsetAsync(d_ws, 0, (size_t)WS_ZERO_FLOATS * 4, stream);

    k1_partials<<<dim3(32, NBATCH),        256, 0, stream>>>(x, w_qkv, ws);
    k2_mprime  <<<dim3(NBATCH, 4),         256, 0, stream>>>(w_qkv, w_out, ws, Mbf);
    k3_out     <<<dim3(NPIX / 64, NBATCH), 256, 0, stream>>>(x, b_out, Mbf, y);
}